// Round 5
// baseline (276.118 us; speedup 1.0000x reference)
//
#include <hip/hip_runtime.h>
#include <hip/hip_bf16.h>

#define D_MODEL 1024
#define NHEADS 16
#define DKH 64
#define BATCH 4
#define SEQ 2048
#define MROWS (BATCH*SEQ)                 // 8192
#define BSD ((size_t)MROWS * D_MODEL)     // 8388608 elements
#define WSZ ((size_t)D_MODEL * D_MODEL)   // 1048576 elements
#define LOG2E 1.4426950408889634f
#define NT (SEQ/64)                       // 32 KV tiles

typedef __attribute__((ext_vector_type(8)))  short   s16x8;
typedef __attribute__((ext_vector_type(8)))  __bf16  bf16x8;
typedef __attribute__((ext_vector_type(4)))  __bf16  bf16x4;
typedef __attribute__((ext_vector_type(4)))  float   f32x4;
typedef __attribute__((ext_vector_type(16))) float   f32x16;

// XOR-swizzled LDS index for [N][64]-bf16 tiles (row stride 128B).
#define SWZ(row, scol) ((((int)(row)) << 6) + (((int)(scol)) ^ ((((int)(row)) & 7) << 3)))

__device__ inline short f2bf(float f) {
    __bf16 h = (__bf16)f;
    short s; __builtin_memcpy(&s, &h, 2); return s;
}

// packed RNE f32x2 -> bf16x2 (T12 recipe: no builtin for cvt_pk on gfx950)
__device__ inline unsigned pk2(float a, float b) {
    unsigned r;
    asm("v_cvt_pk_bf16_f32 %0, %1, %2" : "=v"(r) : "v"(a), "v"(b));
    return r;
}
__device__ inline bf16x8 mk8(unsigned w0, unsigned w1, unsigned w2, unsigned w3) {
    union { unsigned u[4]; bf16x8 v; } x;
    x.u[0] = w0; x.u[1] = w1; x.u[2] = w2; x.u[3] = w3;
    return x.v;
}

__device__ inline void gl_lds16(const void* g, void* l) {
    __builtin_amdgcn_global_load_lds(
        (const __attribute__((address_space(1))) unsigned*)g,
        (__attribute__((address_space(3))) unsigned*)l, 16, 0, 0);
}

// ---------------------------------------------------------------------------
// f32 -> bf16 conversion, weights only (4 buffers of WSZ). Grid 4*512.
// ---------------------------------------------------------------------------
struct CvtPtrs { const float* src[4]; short* dst[4]; };

__global__ __launch_bounds__(256) void cvt_w(CvtPtrs p)
{
    const int bx = blockIdx.x;
    const int buf = bx >> 9, boff = bx & 511;
    const float* __restrict__ src = p.src[buf];
    short* __restrict__ dst = p.dst[buf];
    const size_t i = ((size_t)boff * 256 + threadIdx.x) * 8;
    const float4 a = *(const float4*)(src + i);
    const float4 b = *(const float4*)(src + i + 4);
    s16x8 v;
    v[0]=f2bf(a.x); v[1]=f2bf(a.y); v[2]=f2bf(a.z); v[3]=f2bf(a.w);
    v[4]=f2bf(b.x); v[5]=f2bf(b.y); v[6]=f2bf(b.z); v[7]=f2bf(b.w);
    *(s16x8*)(dst + i) = v;
}

// ---------------------------------------------------------------------------
// GEMM body: C[m,n] = sum_k A[m,k]*W[n,k] + bias[n]
// AMODE 0: A fp32, reg-staged with convert. AMODE 1: A bf16 via global_load_lds.
// OMODE 1: bf16 out, head-split (B,H,S,DKH), scaled. OMODE 0: fp32 flat out.
// Tile 128x128, BK=64, 4 waves, 16x16x32 MFMA.
// ---------------------------------------------------------------------------
template<int AMODE, int OMODE>
__device__ __forceinline__ void gemm_body(
    const void* __restrict__ Ain, const short* __restrict__ W,
    const float* __restrict__ bias, void* __restrict__ Cout, float scale)
{
    __shared__ __align__(16) short As[128 * 64];
    __shared__ __align__(16) short Bs[128 * 64];
    const int t   = threadIdx.x;
    const int l   = t & 63;
    const int wid = t >> 6;
    const int g   = l >> 4, r16 = l & 15;
    const int wm  = wid >> 1, wn = wid & 1;
    const int m0  = blockIdx.y * 128, n0 = blockIdx.x * 128;
    const int srow = t >> 3;          // 0..31
    const int scol = (t & 7) * 8;     // element offset within BK=64

    f32x4 acc[4][4];
    #pragma unroll
    for (int mi = 0; mi < 4; ++mi)
        #pragma unroll
        for (int ni = 0; ni < 4; ++ni)
            acc[mi][ni] = (f32x4)0.0f;

    const short* Wp = W + (size_t)(n0 + srow) * D_MODEL + scol;
    short* AsW = As + wid * 512;   // wave-uniform LDS base for gl_lds
    short* BsW = Bs + wid * 512;

    for (int k0 = 0; k0 < D_MODEL; k0 += 64) {
        #pragma unroll
        for (int p = 0; p < 4; ++p) {
            const int row = srow + p * 32;
            if (AMODE == 0) {
                const float* ap = (const float*)Ain + (size_t)(m0 + row) * D_MODEL + k0 + scol;
                const float4 x = *(const float4*)(ap);
                const float4 y = *(const float4*)(ap + 4);
                s16x8 av;
                av[0]=f2bf(x.x); av[1]=f2bf(x.y); av[2]=f2bf(x.z); av[3]=f2bf(x.w);
                av[4]=f2bf(y.x); av[5]=f2bf(y.y); av[6]=f2bf(y.z); av[7]=f2bf(y.w);
                *(s16x8*)&As[row * 64 + scol] = av;
            } else {
                const short* Ap = (const short*)Ain + (size_t)(m0 + srow) * D_MODEL + scol;
                gl_lds16(Ap + (size_t)p * 32 * D_MODEL + k0, AsW + p * 2048);
            }
            gl_lds16(Wp + (size_t)p * 32 * D_MODEL + k0, BsW + p * 2048);
        }
        __syncthreads();
        #pragma unroll
        for (int kc = 0; kc < 2; ++kc) {
            bf16x8 a[4], b[4];
            #pragma unroll
            for (int mi = 0; mi < 4; ++mi)
                a[mi] = *(const bf16x8*)&As[(wm * 64 + mi * 16 + r16) * 64 + kc * 32 + g * 8];
            #pragma unroll
            for (int ni = 0; ni < 4; ++ni)
                b[ni] = *(const bf16x8*)&Bs[(wn * 64 + ni * 16 + r16) * 64 + kc * 32 + g * 8];
            #pragma unroll
            for (int mi = 0; mi < 4; ++mi)
                #pragma unroll
                for (int ni = 0; ni < 4; ++ni)
                    acc[mi][ni] = __builtin_amdgcn_mfma_f32_16x16x32_bf16(a[mi], b[ni], acc[mi][ni], 0, 0, 0);
        }
        __syncthreads();
    }

    #pragma unroll
    for (int mi = 0; mi < 4; ++mi)
        #pragma unroll
        for (int ni = 0; ni < 4; ++ni)
            #pragma unroll
            for (int j = 0; j < 4; ++j) {
                const int m = m0 + wm * 64 + mi * 16 + g * 4 + j;
                const int n = n0 + wn * 64 + ni * 16 + r16;
                float v = acc[mi][ni][j] + bias[n];
                if (OMODE == 1) {
                    v *= scale;
                    const size_t idx = (((size_t)((m >> 11) * NHEADS + (n >> 6)) << 11)
                                        + (size_t)(m & 2047)) * DKH + (n & 63);
                    ((short*)Cout)[idx] = f2bf(v);
                } else {
                    ((float*)Cout)[(size_t)m * D_MODEL + n] = v;
                }
            }
}

struct QkvArgs {
    const float* A[3]; const short* W[3]; const float* bias[3];
    short* out[3]; float scale[3];
};

__global__ __launch_bounds__(256, 2) void gemm_qkv(QkvArgs q) {
    const int z = blockIdx.z;
    gemm_body<0, 1>(q.A[z], q.W[z], q.bias[z], q.out[z], q.scale[z]);
}

__global__ __launch_bounds__(256, 2) void gemm_out(
    const short* A, const short* W, const float* bias, float* C) {
    gemm_body<1, 0>(A, W, bias, C, 1.0f);
}

// ---------------------------------------------------------------------------
// V transpose: (BH, S, 64) bf16 -> (BH, 64, S) bf16
// ---------------------------------------------------------------------------
__global__ __launch_bounds__(256) void transpose_v(
    const short* __restrict__ Vb, short* __restrict__ Vt)
{
    __shared__ __align__(16) short T[64][72];
    const int t  = threadIdx.x;
    const int bh = blockIdx.y;
    const int s0 = blockIdx.x * 64;
    const int row = t >> 2, cb = (t & 3) * 16;
    const short* src = Vb + ((size_t)bh * SEQ + s0 + row) * DKH + cb;
    *(s16x8*)&T[row][cb]     = *(const s16x8*)(src);
    *(s16x8*)&T[row][cb + 8] = *(const s16x8*)(src + 8);
    __syncthreads();
    const int d = t >> 2, sb = (t & 3) * 16;
    s16x8 o0, o1;
    #pragma unroll
    for (int j = 0; j < 8; ++j) { o0[j] = T[sb + j][d]; o1[j] = T[sb + 8 + j][d]; }
    short* dst = Vt + ((size_t)bh * DKH + d) * SEQ + s0 + sb;
    *(s16x8*)(dst)     = o0;
    *(s16x8*)(dst + 8) = o1;
}

// ---------------------------------------------------------------------------
// Flash attention, 32x32x16 MFMA, swapped operands, P in registers (T12),
// K/V double-buffered in LDS (buf1 overlays dead Q region) -> 1 barrier/tile.
// Q pre-scaled by 0.125*log2(e). S^T = mfma(K, Q^T); O^T = mfma(Vt, P^T).
// Lane owns one q-column (lane&31); hi bit (lane>>5) splits the k/d rows.
// Block: 4 waves x 32 q = 128 q-rows; KV tile 64; LDS 32 KB.
// ---------------------------------------------------------------------------
__global__ __launch_bounds__(256, 4) void attn_mfma(
    const short* __restrict__ Qg, const short* __restrict__ Kg,
    const short* __restrict__ Vtg, short* __restrict__ Ab)
{
    __shared__ __align__(16) short lds[16384];   // 32 KB
    // layout (shorts): Q 0..8192 (dies) -> buf1 {K@0, V@4096}; buf0 {K@8192, V@12288}
    const int t   = threadIdx.x;
    const int l   = t & 63;
    const int wid = t >> 6;
    const int l31 = l & 31, hi = l >> 5;
    const int bh  = blockIdx.y, b = bh >> 4, h = bh & 15;
    const int q0  = blockIdx.x * 128;
    const int wq0 = wid * 32;
    const int srow = t >> 3, scol = (t & 7) * 8;   // Q staging
    const int kr = t >> 2, kcb = (t & 3) * 16;     // K/V staging

    // stage Q tile (128 x 64) at base 0, swizzled
    #pragma unroll
    for (int p = 0; p < 4; ++p) {
        const int row = srow + p * 32;
        *(s16x8*)&lds[SWZ(row, scol)] =
            *(const s16x8*)&Qg[((size_t)bh * SEQ + q0 + row) * DKH + scol];
    }
    const short* Kbase = Kg  + (size_t)bh * SEQ * DKH;
    const short* Vbase = Vtg + (size_t)bh * DKH * SEQ;
    // prefetch KV tile 0 into registers
    s16x8 kpf0 = *(const s16x8*)&Kbase[(size_t)kr * DKH + kcb];
    s16x8 kpf1 = *(const s16x8*)&Kbase[(size_t)kr * DKH + kcb + 8];
    s16x8 vpf0 = *(const s16x8*)&Vbase[(size_t)kr * SEQ + kcb];
    s16x8 vpf1 = *(const s16x8*)&Vbase[(size_t)kr * SEQ + kcb + 8];
    __syncthreads();

    // hoist Q fragments: B-operand of 32x32x16, lane holds col q = wq0+l31,
    // d-slice = kc*16 + hi*8 .. +8
    bf16x8 bq[4];
    #pragma unroll
    for (int kc = 0; kc < 4; ++kc)
        bq[kc] = *(const bf16x8*)&lds[SWZ(wq0 + l31, kc * 16 + hi * 8)];

    // tile0 -> buf0 (does not touch Q region; other waves may still be hoisting)
    *(s16x8*)&lds[8192  + SWZ(kr, kcb)]     = kpf0;
    *(s16x8*)&lds[8192  + SWZ(kr, kcb + 8)] = kpf1;
    *(s16x8*)&lds[12288 + SWZ(kr, kcb)]     = vpf0;
    *(s16x8*)&lds[12288 + SWZ(kr, kcb + 8)] = vpf1;
    // issue tile1 loads
    kpf0 = *(const s16x8*)&Kbase[(size_t)(64 + kr) * DKH + kcb];
    kpf1 = *(const s16x8*)&Kbase[(size_t)(64 + kr) * DKH + kcb + 8];
    vpf0 = *(const s16x8*)&Vbase[(size_t)kr * SEQ + 64 + kcb];
    vpf1 = *(const s16x8*)&Vbase[(size_t)kr * SEQ + 64 + kcb + 8];
    __syncthreads();   // buf0 ready; Q region dead in all waves

    f32x16 o0 = (f32x16)0.0f, o1 = (f32x16)0.0f;
    float m_r = -1e30f, l_r = 0.0f;

    for (int kt = 0; kt < NT; ++kt) {
        const int cur = kt & 1;
        const int KO = cur ? 0     : 8192;
        const int VO = cur ? 4096  : 12288;
        const int KN = cur ? 8192  : 0;
        const int VN = cur ? 12288 : 4096;
        // write prefetched tile t+1 into the other buffer (retired by last barrier)
        if (kt + 1 < NT) {
            *(s16x8*)&lds[KN + SWZ(kr, kcb)]     = kpf0;
            *(s16x8*)&lds[KN + SWZ(kr, kcb + 8)] = kpf1;
            *(s16x8*)&lds[VN + SWZ(kr, kcb)]     = vpf0;
            *(s16x8*)&lds[VN + SWZ(kr, kcb + 8)] = vpf1;
        }
        // issue loads for tile t+2 (land during this tile's compute)
        if (kt + 2 < NT) {
            kpf0 = *(const s16x8*)&Kbase[(size_t)((kt + 2) * 64 + kr) * DKH + kcb];
            kpf1 = *(const s16x8*)&Kbase[(size_t)((kt + 2) * 64 + kr) * DKH + kcb + 8];
            vpf0 = *(const s16x8*)&Vbase[(size_t)kr * SEQ + (kt + 2) * 64 + kcb];
            vpf1 = *(const s16x8*)&Vbase[(size_t)kr * SEQ + (kt + 2) * 64 + kcb + 8];
        }

        // S^T = K Q^T: rows k (two 32-blocks), col q = l31
        f32x16 s0 = (f32x16)0.0f, s1 = (f32x16)0.0f;
        __builtin_amdgcn_s_setprio(1);
        #pragma unroll
        for (int kc = 0; kc < 4; ++kc) {
            const bf16x8 ak0 = *(const bf16x8*)&lds[KO + SWZ(l31,      kc * 16 + hi * 8)];
            const bf16x8 ak1 = *(const bf16x8*)&lds[KO + SWZ(32 + l31, kc * 16 + hi * 8)];
            s0 = __builtin_amdgcn_mfma_f32_32x32x16_bf16(ak0, bq[kc], s0, 0, 0, 0);
            s1 = __builtin_amdgcn_mfma_f32_32x32x16_bf16(ak1, bq[kc], s1, 0, 0, 0);
        }
        __builtin_amdgcn_s_setprio(0);

        // lane-local online softmax (exp2 domain), defer-max THR=8
        float mx = s0[0];
        #pragma unroll
        for (int r = 1; r < 16; ++r) mx = fmaxf(mx, s0[r]);
        #pragma unroll
        for (int r = 0; r < 16; ++r) mx = fmaxf(mx, s1[r]);
        mx = fmaxf(mx, __shfl_xor(mx, 32));
        if (__any(mx > m_r + 8.0f)) {
            const float mnew = fmaxf(m_r, mx);
            const float resc = __builtin_amdgcn_exp2f(m_r - mnew);
            m_r = mnew;
            l_r *= resc;
            #pragma unroll
            for (int r = 0; r < 16; ++r) { o0[r] *= resc; o1[r] *= resc; }
        }
        float sum = 0.0f;
        #pragma unroll
        for (int r = 0; r < 16; ++r) {
            const float p = __builtin_amdgcn_exp2f(s0[r] - m_r);
            s0[r] = p; sum += p;
        }
        #pragma unroll
        for (int r = 0; r < 16; ++r) {
            const float p = __builtin_amdgcn_exp2f(s1[r] - m_r);
            s1[r] = p; sum += p;
        }
        l_r += sum;

        // T12: pack P to bf16 words and redistribute via permlane32_swap so each
        // lane holds its PV B-operand k-slice in-register (no LDS round-trip).
        bf16x8 bp[4];
        {
            unsigned a0 = pk2(s0[0], s0[1]),  b0 = pk2(s0[4],  s0[5]);
            unsigned a1 = pk2(s0[2], s0[3]),  b1 = pk2(s0[6],  s0[7]);
            asm("v_permlane32_swap_b32 %0, %1" : "+v"(a0), "+v"(b0));
            asm("v_permlane32_swap_b32 %0, %1" : "+v"(a1), "+v"(b1));
            bp[0] = mk8(a0, a1, b0, b1);
            unsigned a2 = pk2(s0[8], s0[9]),   b2 = pk2(s0[12], s0[13]);
            unsigned a3 = pk2(s0[10], s0[11]), b3 = pk2(s0[14], s0[15]);
            asm("v_permlane32_swap_b32 %0, %1" : "+v"(a2), "+v"(b2));
            asm("v_permlane32_swap_b32 %0, %1" : "+v"(a3), "+v"(b3));
            bp[1] = mk8(a2, a3, b2, b3);
        }
        {
            unsigned a0 = pk2(s1[0], s1[1]),  b0 = pk2(s1[4],  s1[5]);
            unsigned a1 = pk2(s1[2], s1[3]),  b1 = pk2(s1[6],  s1[7]);
            asm("v_permlane32_swap_b32 %0, %1" : "+v"(a0), "+v"(b0));
            asm("v_permlane32_swap_b32 %0, %1" : "+v"(a1), "+v"(b1));
            bp[2] = mk8(a0, a1, b0, b1);
            unsigned a2 = pk2(s1[8], s1[9]),   b2 = pk2(s1[12], s1[13]);
            unsigned a3 = pk2(s1[10], s1[11]), b3 = pk2(s1[14], s1[15]);
            asm("v_permlane32_swap_b32 %0, %1" : "+v"(a2), "+v"(b2));
            asm("v_permlane32_swap_b32 %0, %1" : "+v"(a3), "+v"(b3));
            bp[3] = mk8(a2, a3, b2, b3);
        }

        // O^T += V^T P^T: rows d (two 32-blocks), col q = l31
        __builtin_amdgcn_s_setprio(1);
        #pragma unroll
        for (int ks = 0; ks < 4; ++ks) {
            const bf16x8 av0 = *(const bf16x8*)&lds[VO + SWZ(l31,      ks * 16 + hi * 8)];
            const bf16x8 av1 = *(const bf16x8*)&lds[VO + SWZ(32 + l31, ks * 16 + hi * 8)];
            o0 = __builtin_amdgcn_mfma_f32_32x32x16_bf16(av0, bp[ks], o0, 0, 0, 0);
            o1 = __builtin_amdgcn_mfma_f32_32x32x16_bf16(av1, bp[ks], o1, 0, 0, 0);
        }
        __builtin_amdgcn_s_setprio(0);

        __syncthreads();   // all waves done with buf[cur]; buf[next] writes visible
    }

    // epilogue: reduce l across the hi-pair, normalize, write O (B,S,D) bf16
    const float lt = l_r + __shfl_xor(l_r, 32);
    const float inv = 1.0f / lt;
    const int q = q0 + wq0 + l31;
    short* Op = Ab + ((size_t)b * SEQ + q) * D_MODEL + h * DKH;
    #pragma unroll
    for (int rr = 0; rr < 4; ++rr) {
        bf16x4 ov;
        ov[0] = (__bf16)(o0[rr*4+0] * inv); ov[1] = (__bf16)(o0[rr*4+1] * inv);
        ov[2] = (__bf16)(o0[rr*4+2] * inv); ov[3] = (__bf16)(o0[rr*4+3] * inv);
        *(bf16x4*)&Op[rr * 8 + hi * 4] = ov;
        bf16x4 ow;
        ow[0] = (__bf16)(o1[rr*4+0] * inv); ow[1] = (__bf16)(o1[rr*4+1] * inv);
        ow[2] = (__bf16)(o1[rr*4+2] * inv); ow[3] = (__bf16)(o1[rr*4+3] * inv);
        *(bf16x4*)&Op[32 + rr * 8 + hi * 4] = ow;
    }
}

extern "C" void kernel_launch(void* const* d_in, const int* in_sizes, int n_in,
                              void* d_out, int out_size, void* d_ws, size_t ws_size,
                              hipStream_t stream) {
    const float* q_in = (const float*)d_in[0];
    const float* k_in = (const float*)d_in[1];
    const float* v_in = (const float*)d_in[2];
    const float* w_q  = (const float*)d_in[3];
    const float* b_q  = (const float*)d_in[4];
    const float* w_k  = (const float*)d_in[5];
    const float* b_k  = (const float*)d_in[6];
    const float* w_v  = (const float*)d_in[7];
    const float* b_v  = (const float*)d_in[8];
    const float* w_o  = (const float*)d_in[9];
    const float* b_o  = (const float*)d_in[10];
    float* out = (float*)d_out;

    short* ws = (short*)d_ws;
    short* Wq = ws;                   // bf16 weights
    short* Wk = Wq + WSZ;
    short* Wv = Wk + WSZ;
    short* Wo = Wv + WSZ;
    short* Qb = ws + 4 * WSZ;         // (B*H,S,64) bf16, pre-scaled
    short* Kb = Qb + BSD;
    short* Vb = Kb + BSD;
    short* Vt = Vb + BSD;             // (B*H,64,S) bf16
    short* Ab = Vt + BSD;             // (B,S,D) bf16 attn output

    dim3 blk(256);

    CvtPtrs cp;
    cp.src[0] = w_q; cp.dst[0] = Wq;
    cp.src[1] = w_k; cp.dst[1] = Wk;
    cp.src[2] = w_v; cp.dst[2] = Wv;
    cp.src[3] = w_o; cp.dst[3] = Wo;
    cvt_w<<<dim3(4 * 512), blk, 0, stream>>>(cp);

    QkvArgs qa;
    qa.A[0] = q_in; qa.W[0] = Wq; qa.bias[0] = b_q; qa.out[0] = Qb; qa.scale[0] = 0.125f * LOG2E;
    qa.A[1] = k_in; qa.W[1] = Wk; qa.bias[1] = b_k; qa.out[1] = Kb; qa.scale[1] = 1.0f;
    qa.A[2] = v_in; qa.W[2] = Wv; qa.bias[2] = b_v; qa.out[2] = Vb; qa.scale[2] = 1.0f;
    gemm_qkv<<<dim3(D_MODEL / 128, MROWS / 128, 3), blk, 0, stream>>>(qa);

    transpose_v<<<dim3(SEQ / 64, BATCH * NHEADS), blk, 0, stream>>>(Vb, Vt);

    attn_mfma<<<dim3(SEQ / 128, BATCH * NHEADS), blk, 0, stream>>>(Qb, Kb, Vt, Ab);

    gemm_out<<<dim3(D_MODEL / 128, MROWS / 128), blk, 0, stream>>>(Ab, Wo, b_o, out);
}

// Round 6
// 218.009 us; speedup vs baseline: 1.2665x; 1.2665x over previous
//
#include <hip/hip_runtime.h>
#include <hip/hip_bf16.h>

#define D_MODEL 1024
#define NHEADS 16
#define DKH 64
#define BATCH 4
#define SEQ 2048
#define MROWS (BATCH*SEQ)                 // 8192
#define BSD ((size_t)MROWS * D_MODEL)     // 8388608 elements
#define WSZ ((size_t)D_MODEL * D_MODEL)   // 1048576 elements
#define LOG2E 1.4426950408889634f
#define NT (SEQ/64)                       // 32 KV tiles

typedef __attribute__((ext_vector_type(8)))  short   s16x8;
typedef __attribute__((ext_vector_type(8)))  __bf16  bf16x8;
typedef __attribute__((ext_vector_type(4)))  __bf16  bf16x4;
typedef __attribute__((ext_vector_type(4)))  float   f32x4;
typedef __attribute__((ext_vector_type(16))) float   f32x16;

// XOR-swizzled LDS index for [N][64]-bf16 tiles (row stride 128B).
#define SWZ(row, scol) ((((int)(row)) << 6) + (((int)(scol)) ^ ((((int)(row)) & 7) << 3)))

__device__ inline short f2bf(float f) {
    __bf16 h = (__bf16)f;
    short s; __builtin_memcpy(&s, &h, 2); return s;
}

// packed RNE f32x2 -> bf16x2
__device__ inline unsigned pk2(float a, float b) {
    unsigned r;
    asm("v_cvt_pk_bf16_f32 %0, %1, %2" : "=v"(r) : "v"(a), "v"(b));
    return r;
}
__device__ inline bf16x8 mk8(unsigned w0, unsigned w1, unsigned w2, unsigned w3) {
    union { unsigned u[4]; bf16x8 v; } x;
    x.u[0] = w0; x.u[1] = w1; x.u[2] = w2; x.u[3] = w3;
    return x.v;
}

__device__ inline void gl_lds16(const void* g, void* l) {
    __builtin_amdgcn_global_load_lds(
        (const __attribute__((address_space(1))) unsigned*)g,
        (__attribute__((address_space(3))) unsigned*)l, 16, 0, 0);
}

// ---------------------------------------------------------------------------
// Fused f32 -> bf16 conversion: 3 big (BSD) + 4 weight (WSZ) buffers.
// ---------------------------------------------------------------------------
struct CvtPtrs { const float* src[7]; short* dst[7]; };

__global__ __launch_bounds__(256) void cvt_all(CvtPtrs p)
{
    const int bx = blockIdx.x;
    int buf, boff;
    if (bx < 3 * 4096) { buf = bx >> 12; boff = bx & 4095; }
    else { const int r = bx - 3 * 4096; buf = 3 + (r >> 9); boff = r & 511; }
    const float* __restrict__ src = p.src[buf];
    short* __restrict__ dst = p.dst[buf];
    const size_t i = ((size_t)boff * 256 + threadIdx.x) * 8;
    const float4 a = *(const float4*)(src + i);
    const float4 b = *(const float4*)(src + i + 4);
    s16x8 v;
    v[0]=f2bf(a.x); v[1]=f2bf(a.y); v[2]=f2bf(a.z); v[3]=f2bf(a.w);
    v[4]=f2bf(b.x); v[5]=f2bf(b.y); v[6]=f2bf(b.z); v[7]=f2bf(b.w);
    *(s16x8*)(dst + i) = v;
}

// ---------------------------------------------------------------------------
// GEMM body (bf16 in): C[m,n] = sum_k A[m,k]*W[n,k] + bias[n]
// m97 structure: 128x128 tile, BK=64, global_load_lds width 16, linear LDS.
// XCD-swizzled block ids: each XCD owns an 8-m-tile stripe x all n-tiles
// (A panel 2 MB + W 2 MB -> fits one 4 MB L2).
// OMODE 1: bf16 out, head-split (B,H,S,DKH), scaled. OMODE 0: fp32 flat out.
// ---------------------------------------------------------------------------
template<int OMODE>
__device__ __forceinline__ void gemm_body(
    const short* __restrict__ A, const short* __restrict__ W,
    const float* __restrict__ bias, void* __restrict__ Cout, float scale)
{
    __shared__ __align__(16) short As[128 * 64];
    __shared__ __align__(16) short Bs[128 * 64];
    const int t   = threadIdx.x;
    const int l   = t & 63;
    const int wid = t >> 6;
    const int g   = l >> 4, r16 = l & 15;
    const int wm  = wid >> 1, wn = wid & 1;
    // XCD swizzle: bid%8 = XCD; give each XCD a contiguous swz chunk (512%8==0)
    const int bid = blockIdx.x + (blockIdx.y << 3);
    const int swz = (bid & 7) * 64 + (bid >> 3);
    const int n0  = (swz & 7) * 128, m0 = (swz >> 3) * 128;
    const int srow = t >> 3;          // 0..31
    const int scol = (t & 7) * 8;     // element offset within BK=64

    f32x4 acc[4][4];
    #pragma unroll
    for (int mi = 0; mi < 4; ++mi)
        #pragma unroll
        for (int ni = 0; ni < 4; ++ni)
            acc[mi][ni] = (f32x4)0.0f;

    const short* Ap = A + (size_t)(m0 + srow) * D_MODEL + scol;
    const short* Wp = W + (size_t)(n0 + srow) * D_MODEL + scol;
    short* AsW = As + wid * 512;   // wave-uniform LDS base for gl_lds
    short* BsW = Bs + wid * 512;

    for (int k0 = 0; k0 < D_MODEL; k0 += 64) {
        #pragma unroll
        for (int p = 0; p < 4; ++p) {
            gl_lds16(Ap + (size_t)p * 32 * D_MODEL + k0, AsW + p * 2048);
            gl_lds16(Wp + (size_t)p * 32 * D_MODEL + k0, BsW + p * 2048);
        }
        __syncthreads();
        #pragma unroll
        for (int kc = 0; kc < 2; ++kc) {
            bf16x8 a[4], b[4];
            #pragma unroll
            for (int mi = 0; mi < 4; ++mi)
                a[mi] = *(const bf16x8*)&As[(wm * 64 + mi * 16 + r16) * 64 + kc * 32 + g * 8];
            #pragma unroll
            for (int ni = 0; ni < 4; ++ni)
                b[ni] = *(const bf16x8*)&Bs[(wn * 64 + ni * 16 + r16) * 64 + kc * 32 + g * 8];
            #pragma unroll
            for (int mi = 0; mi < 4; ++mi)
                #pragma unroll
                for (int ni = 0; ni < 4; ++ni)
                    acc[mi][ni] = __builtin_amdgcn_mfma_f32_16x16x32_bf16(a[mi], b[ni], acc[mi][ni], 0, 0, 0);
        }
        __syncthreads();
    }

    #pragma unroll
    for (int mi = 0; mi < 4; ++mi)
        #pragma unroll
        for (int ni = 0; ni < 4; ++ni)
            #pragma unroll
            for (int j = 0; j < 4; ++j) {
                const int m = m0 + wm * 64 + mi * 16 + g * 4 + j;
                const int n = n0 + wn * 64 + ni * 16 + r16;
                float v = acc[mi][ni][j] + bias[n];
                if (OMODE == 1) {
                    v *= scale;
                    const size_t idx = (((size_t)((m >> 11) * NHEADS + (n >> 6)) << 11)
                                        + (size_t)(m & 2047)) * DKH + (n & 63);
                    ((short*)Cout)[idx] = f2bf(v);
                } else {
                    ((float*)Cout)[(size_t)m * D_MODEL + n] = v;
                }
            }
}

struct QkvArgs {
    const short* A[3]; const short* W[3]; const float* bias[3];
    short* out[3]; float scale[3];
};

__global__ __launch_bounds__(256, 2) void gemm_qkv(QkvArgs q) {
    const int z = blockIdx.z;
    gemm_body<1>(q.A[z], q.W[z], q.bias[z], q.out[z], q.scale[z]);
}

__global__ __launch_bounds__(256, 2) void gemm_out(
    const short* A, const short* W, const float* bias, float* C) {
    gemm_body<0>(A, W, bias, C, 1.0f);
}

// ---------------------------------------------------------------------------
// V transpose: (BH, S, 64) bf16 -> (BH, 64, S) bf16
// ---------------------------------------------------------------------------
__global__ __launch_bounds__(256) void transpose_v(
    const short* __restrict__ Vb, short* __restrict__ Vt)
{
    __shared__ __align__(16) short T[64][72];
    const int t  = threadIdx.x;
    const int bh = blockIdx.y;
    const int s0 = blockIdx.x * 64;
    const int row = t >> 2, cb = (t & 3) * 16;
    const short* src = Vb + ((size_t)bh * SEQ + s0 + row) * DKH + cb;
    *(s16x8*)&T[row][cb]     = *(const s16x8*)(src);
    *(s16x8*)&T[row][cb + 8] = *(const s16x8*)(src + 8);
    __syncthreads();
    const int d = t >> 2, sb = (t & 3) * 16;
    s16x8 o0, o1;
    #pragma unroll
    for (int j = 0; j < 8; ++j) { o0[j] = T[sb + j][d]; o1[j] = T[sb + 8 + j][d]; }
    short* dst = Vt + ((size_t)bh * DKH + d) * SEQ + s0 + sb;
    *(s16x8*)(dst)     = o0;
    *(s16x8*)(dst + 8) = o1;
}

// ---------------------------------------------------------------------------
// Flash attention, 32x32x16 MFMA, swapped operands, P in registers (T12),
// K/V double-buffered in LDS (buf1 overlays dead Q region) -> 1 barrier/tile.
// launch_bounds(256,3): 170-reg budget (no spill; est ~150 used), 3 blocks/CU.
// XCD swizzle: each XCD owns 8 complete heads -> KV working set 4 MB = one L2.
// ---------------------------------------------------------------------------
__global__ __launch_bounds__(256, 3) void attn_mfma(
    const short* __restrict__ Qg, const short* __restrict__ Kg,
    const short* __restrict__ Vtg, short* __restrict__ Ab)
{
    __shared__ __align__(16) short lds[16384];   // 32 KB
    // layout (shorts): Q 0..8192 (dies) -> buf1 {K@0, V@4096}; buf0 {K@8192, V@12288}
    const int t   = threadIdx.x;
    const int l   = t & 63;
    const int wid = t >> 6;
    const int l31 = l & 31, hi = l >> 5;
    // XCD swizzle (1024 blocks, 1024%8==0): XCD c gets bh c*8..c*8+7, all q-tiles
    const int bid = blockIdx.x + (blockIdx.y << 4);
    const int swz = (bid & 7) * 128 + (bid >> 3);
    const int bh  = swz >> 4, b = bh >> 4, h = bh & 15;
    const int q0  = (swz & 15) << 7;
    const int wq0 = wid * 32;
    const int srow = t >> 3, scol = (t & 7) * 8;   // Q staging
    const int kr = t >> 2, kcb = (t & 3) * 16;     // K/V staging

    // stage Q tile (128 x 64) at base 0, swizzled
    #pragma unroll
    for (int p = 0; p < 4; ++p) {
        const int row = srow + p * 32;
        *(s16x8*)&lds[SWZ(row, scol)] =
            *(const s16x8*)&Qg[((size_t)bh * SEQ + q0 + row) * DKH + scol];
    }
    const short* Kbase = Kg  + (size_t)bh * SEQ * DKH;
    const short* Vbase = Vtg + (size_t)bh * DKH * SEQ;
    // prefetch KV tile 0 into registers
    s16x8 kpf0 = *(const s16x8*)&Kbase[(size_t)kr * DKH + kcb];
    s16x8 kpf1 = *(const s16x8*)&Kbase[(size_t)kr * DKH + kcb + 8];
    s16x8 vpf0 = *(const s16x8*)&Vbase[(size_t)kr * SEQ + kcb];
    s16x8 vpf1 = *(const s16x8*)&Vbase[(size_t)kr * SEQ + kcb + 8];
    __syncthreads();

    // hoist Q fragments: B-operand of 32x32x16, lane holds col q = wq0+l31
    bf16x8 bq[4];
    #pragma unroll
    for (int kc = 0; kc < 4; ++kc)
        bq[kc] = *(const bf16x8*)&lds[SWZ(wq0 + l31, kc * 16 + hi * 8)];

    // tile0 -> buf0 (does not touch Q region; other waves may still be hoisting)
    *(s16x8*)&lds[8192  + SWZ(kr, kcb)]     = kpf0;
    *(s16x8*)&lds[8192  + SWZ(kr, kcb + 8)] = kpf1;
    *(s16x8*)&lds[12288 + SWZ(kr, kcb)]     = vpf0;
    *(s16x8*)&lds[12288 + SWZ(kr, kcb + 8)] = vpf1;
    // issue tile1 loads
    kpf0 = *(const s16x8*)&Kbase[(size_t)(64 + kr) * DKH + kcb];
    kpf1 = *(const s16x8*)&Kbase[(size_t)(64 + kr) * DKH + kcb + 8];
    vpf0 = *(const s16x8*)&Vbase[(size_t)kr * SEQ + 64 + kcb];
    vpf1 = *(const s16x8*)&Vbase[(size_t)kr * SEQ + 64 + kcb + 8];
    __syncthreads();   // buf0 ready; Q region dead in all waves

    f32x16 o0 = (f32x16)0.0f, o1 = (f32x16)0.0f;
    float m_r = -1e30f, l_r = 0.0f;

    for (int kt = 0; kt < NT; ++kt) {
        const int cur = kt & 1;
        const int KO = cur ? 0     : 8192;
        const int VO = cur ? 4096  : 12288;
        const int KN = cur ? 8192  : 0;
        const int VN = cur ? 12288 : 4096;
        // write prefetched tile t+1 into the other buffer (retired by last barrier)
        if (kt + 1 < NT) {
            *(s16x8*)&lds[KN + SWZ(kr, kcb)]     = kpf0;
            *(s16x8*)&lds[KN + SWZ(kr, kcb + 8)] = kpf1;
            *(s16x8*)&lds[VN + SWZ(kr, kcb)]     = vpf0;
            *(s16x8*)&lds[VN + SWZ(kr, kcb + 8)] = vpf1;
        }
        // issue loads for tile t+2 (land during this tile's compute)
        if (kt + 2 < NT) {
            kpf0 = *(const s16x8*)&Kbase[(size_t)((kt + 2) * 64 + kr) * DKH + kcb];
            kpf1 = *(const s16x8*)&Kbase[(size_t)((kt + 2) * 64 + kr) * DKH + kcb + 8];
            vpf0 = *(const s16x8*)&Vbase[(size_t)kr * SEQ + (kt + 2) * 64 + kcb];
            vpf1 = *(const s16x8*)&Vbase[(size_t)kr * SEQ + (kt + 2) * 64 + kcb + 8];
        }

        // S^T = K Q^T: rows k (two 32-blocks), col q = l31
        f32x16 s0 = (f32x16)0.0f, s1 = (f32x16)0.0f;
        __builtin_amdgcn_s_setprio(1);
        #pragma unroll
        for (int kc = 0; kc < 4; ++kc) {
            const bf16x8 ak0 = *(const bf16x8*)&lds[KO + SWZ(l31,      kc * 16 + hi * 8)];
            const bf16x8 ak1 = *(const bf16x8*)&lds[KO + SWZ(32 + l31, kc * 16 + hi * 8)];
            s0 = __builtin_amdgcn_mfma_f32_32x32x16_bf16(ak0, bq[kc], s0, 0, 0, 0);
            s1 = __builtin_amdgcn_mfma_f32_32x32x16_bf16(ak1, bq[kc], s1, 0, 0, 0);
        }
        __builtin_amdgcn_s_setprio(0);

        // lane-local online softmax (exp2 domain), defer-max THR=8
        float mx = s0[0];
        #pragma unroll
        for (int r = 1; r < 16; ++r) mx = fmaxf(mx, s0[r]);
        #pragma unroll
        for (int r = 0; r < 16; ++r) mx = fmaxf(mx, s1[r]);
        mx = fmaxf(mx, __shfl_xor(mx, 32));
        if (__any(mx > m_r + 8.0f)) {
            const float mnew = fmaxf(m_r, mx);
            const float resc = __builtin_amdgcn_exp2f(m_r - mnew);
            m_r = mnew;
            l_r *= resc;
            #pragma unroll
            for (int r = 0; r < 16; ++r) { o0[r] *= resc; o1[r] *= resc; }
        }
        float sum = 0.0f;
        #pragma unroll
        for (int r = 0; r < 16; ++r) {
            const float p = __builtin_amdgcn_exp2f(s0[r] - m_r);
            s0[r] = p; sum += p;
        }
        #pragma unroll
        for (int r = 0; r < 16; ++r) {
            const float p = __builtin_amdgcn_exp2f(s1[r] - m_r);
            s1[r] = p; sum += p;
        }
        l_r += sum;

        // T12: pack P to bf16 and redistribute via permlane32_swap so each lane
        // holds its PV B-operand k-slice in-register (no LDS round-trip).
        bf16x8 bp[4];
        {
            unsigned a0 = pk2(s0[0], s0[1]),  b0 = pk2(s0[4],  s0[5]);
            unsigned a1 = pk2(s0[2], s0[3]),  b1 = pk2(s0[6],  s0[7]);
            asm("v_permlane32_swap_b32 %0, %1" : "+v"(a0), "+v"(b0));
            asm("v_permlane32_swap_b32 %0, %1" : "+v"(a1), "+v"(b1));
            bp[0] = mk8(a0, a1, b0, b1);
            unsigned a2 = pk2(s0[8], s0[9]),   b2 = pk2(s0[12], s0[13]);
            unsigned a3 = pk2(s0[10], s0[11]), b3 = pk2(s0[14], s0[15]);
            asm("v_permlane32_swap_b32 %0, %1" : "+v"(a2), "+v"(b2));
            asm("v_permlane32_swap_b32 %0, %1" : "+v"(a3), "+v"(b3));
            bp[1] = mk8(a2, a3, b2, b3);
        }
        {
            unsigned a0 = pk2(s1[0], s1[1]),  b0 = pk2(s1[4],  s1[5]);
            unsigned a1 = pk2(s1[2], s1[3]),  b1 = pk2(s1[6],  s1[7]);
            asm("v_permlane32_swap_b32 %0, %1" : "+v"(a0), "+v"(b0));
            asm("v_permlane32_swap_b32 %0, %1" : "+v"(a1), "+v"(b1));
            bp[2] = mk8(a0, a1, b0, b1);
            unsigned a2 = pk2(s1[8], s1[9]),   b2 = pk2(s1[12], s1[13]);
            unsigned a3 = pk2(s1[10], s1[11]), b3 = pk2(s1[14], s1[15]);
            asm("v_permlane32_swap_b32 %0, %1" : "+v"(a2), "+v"(b2));
            asm("v_permlane32_swap_b32 %0, %1" : "+v"(a3), "+v"(b3));
            bp[3] = mk8(a2, a3, b2, b3);
        }

        // O^T += V^T P^T: rows d (two 32-blocks), col q = l31
        __builtin_amdgcn_s_setprio(1);
        #pragma unroll
        for (int ks = 0; ks < 4; ++ks) {
            const bf16x8 av0 = *(const bf16x8*)&lds[VO + SWZ(l31,      ks * 16 + hi * 8)];
            const bf16x8 av1 = *(const bf16x8*)&lds[VO + SWZ(32 + l31, ks * 16 + hi * 8)];
            o0 = __builtin_amdgcn_mfma_f32_32x32x16_bf16(av0, bp[ks], o0, 0, 0, 0);
            o1 = __builtin_amdgcn_mfma_f32_32x32x16_bf16(av1, bp[ks], o1, 0, 0, 0);
        }
        __builtin_amdgcn_s_setprio(0);

        __syncthreads();   // all waves done with buf[cur]; buf[next] writes visible
    }

    // epilogue: reduce l across the hi-pair, normalize, write O (B,S,D) bf16
    const float lt = l_r + __shfl_xor(l_r, 32);
    const float inv = 1.0f / lt;
    const int q = q0 + wq0 + l31;
    short* Op = Ab + ((size_t)b * SEQ + q) * D_MODEL + h * DKH;
    #pragma unroll
    for (int rr = 0; rr < 4; ++rr) {
        bf16x4 ov;
        ov[0] = (__bf16)(o0[rr*4+0] * inv); ov[1] = (__bf16)(o0[rr*4+1] * inv);
        ov[2] = (__bf16)(o0[rr*4+2] * inv); ov[3] = (__bf16)(o0[rr*4+3] * inv);
        *(bf16x4*)&Op[rr * 8 + hi * 4] = ov;
        bf16x4 ow;
        ow[0] = (__bf16)(o1[rr*4+0] * inv); ow[1] = (__bf16)(o1[rr*4+1] * inv);
        ow[2] = (__bf16)(o1[rr*4+2] * inv); ow[3] = (__bf16)(o1[rr*4+3] * inv);
        *(bf16x4*)&Op[32 + rr * 8 + hi * 4] = ow;
    }
}

extern "C" void kernel_launch(void* const* d_in, const int* in_sizes, int n_in,
                              void* d_out, int out_size, void* d_ws, size_t ws_size,
                              hipStream_t stream) {
    const float* q_in = (const float*)d_in[0];
    const float* k_in = (const float*)d_in[1];
    const float* v_in = (const float*)d_in[2];
    const float* w_q  = (const float*)d_in[3];
    const float* b_q  = (const float*)d_in[4];
    const float* w_k  = (const float*)d_in[5];
    const float* b_k  = (const float*)d_in[6];
    const float* w_v  = (const float*)d_in[7];
    const float* b_v  = (const float*)d_in[8];
    const float* w_o  = (const float*)d_in[9];
    const float* b_o  = (const float*)d_in[10];
    float* out = (float*)d_out;

    short* ws = (short*)d_ws;
    short* Qc = ws;                   // bf16 copies of inputs
    short* Kc = ws + BSD;
    short* Vc = ws + 2 * BSD;
    short* Wq = ws + 3 * BSD;
    short* Wk = Wq + WSZ;
    short* Wv = Wk + WSZ;
    short* Wo = Wv + WSZ;
    short* Qb = ws + 3 * BSD + 4 * WSZ;   // (B*H,S,64) bf16, pre-scaled
    short* Kb = Qb + BSD;
    short* Vb = Kb + BSD;
    short* Vt = Qc;                       // alias: Qc dead after Q-proj
    short* Ab = Kc;                       // alias: Kc dead after K-proj

    dim3 blk(256);

    CvtPtrs cp;
    cp.src[0] = q_in; cp.dst[0] = Qc;
    cp.src[1] = k_in; cp.dst[1] = Kc;
    cp.src[2] = v_in; cp.dst[2] = Vc;
    cp.src[3] = w_q;  cp.dst[3] = Wq;
    cp.src[4] = w_k;  cp.dst[4] = Wk;
    cp.src[5] = w_v;  cp.dst[5] = Wv;
    cp.src[6] = w_o;  cp.dst[6] = Wo;
    cvt_all<<<dim3(3 * 4096 + 4 * 512), blk, 0, stream>>>(cp);

    QkvArgs qa;
    qa.A[0] = Qc; qa.W[0] = Wq; qa.bias[0] = b_q; qa.out[0] = Qb; qa.scale[0] = 0.125f * LOG2E;
    qa.A[1] = Kc; qa.W[1] = Wk; qa.bias[1] = b_k; qa.out[1] = Kb; qa.scale[1] = 1.0f;
    qa.A[2] = Vc; qa.W[2] = Wv; qa.bias[2] = b_v; qa.out[2] = Vb; qa.scale[2] = 1.0f;
    gemm_qkv<<<dim3(D_MODEL / 128, MROWS / 128, 3), blk, 0, stream>>>(qa);

    transpose_v<<<dim3(SEQ / 64, BATCH * NHEADS), blk, 0, stream>>>(Vb, Vt);

    attn_mfma<<<dim3(SEQ / 128, BATCH * NHEADS), blk, 0, stream>>>(Qb, Kb, Vt, Ab);

    gemm_out<<<dim3(D_MODEL / 128, MROWS / 128), blk, 0, stream>>>(Ab, Wo, b_o, out);
}